// Round 23
// baseline (29.477 us; speedup 1.0000x reference)
//
#include <hip/hip_runtime.h>
#include <math.h>

#define KK 5
#define WPOUT 28
#define PPI 784          // patches per image (28*28)
#define NCH 64
#define NPAIR 12544      // patch pairs (A=2k, B=2k+1 always in same row: 28 even)
#define HPAIR 6272       // half the pairs go to the register pipeline, half to the LDS pipeline
#define THREADS 128
#define NNODE 21
#define SLICE 43         // per-thread LDS slice, dwords: patch h2-pairs [0..24], h0B [26..41]

typedef float f32x32 __attribute__((ext_vector_type(32)));
typedef float f32x16 __attribute__((ext_vector_type(16)));
typedef _Float16 h2  __attribute__((ext_vector_type(2)));

static __device__ __forceinline__ h2 u2h(unsigned u) { return __builtin_bit_cast(h2, u); }
static __device__ __forceinline__ unsigned h2u(h2 h) { return __builtin_bit_cast(unsigned, h); }
static __device__ __forceinline__ unsigned f2u(float f) { return __builtin_bit_cast(unsigned, f); }
static __device__ __forceinline__ float u2f(unsigned u) { return __builtin_bit_cast(float, u); }

// pack two f32 -> packed f16 pair in one dword (v_cvt_pkrtz_f16_f32)
static __device__ __forceinline__ unsigned packpair(float a, float b) {
    const auto pk = __builtin_amdgcn_cvt_pkrtz(a, b);   // __fp16 ext_vector(2)
    return __builtin_bit_cast(unsigned, pk);
}

// r = s * splat(d.half[ODD]) + splat(e.half[ODD])   (packed f16, both output halves)
template <int ODD>
static __device__ __forceinline__ unsigned pkfma_splat(unsigned s, unsigned d, unsigned e) {
    unsigned r;
    if constexpr (ODD)
        asm("v_pk_fma_f16 %0, %1, %2, %3 op_sel:[0,1,1] op_sel_hi:[1,1,1]"
            : "=v"(r) : "v"(s), "v"(d), "v"(e));
    else
        asm("v_pk_fma_f16 %0, %1, %2, %3 op_sel:[0,0,0] op_sel_hi:[1,0,0]"
            : "=v"(r) : "v"(s), "v"(d), "v"(e));
    return r;
}

// One 4-input LUT node for a packed patch pair (both patches in each h2).
static __device__ __forceinline__ unsigned node_pair(uint4 E, uint4 D,
                                                     unsigned s0, unsigned s1,
                                                     unsigned s2, unsigned s3) {
    const unsigned Ea[4] = { E.x, E.y, E.z, E.w };
    const unsigned Da[4] = { D.x, D.y, D.z, D.w };
    unsigned v[8];
#pragma unroll
    for (int k = 0; k < 8; k += 2) {
        v[k]     = pkfma_splat<0>(s3, Da[k >> 1], Ea[k >> 1]);
        v[k + 1] = pkfma_splat<1>(s3, Da[k >> 1], Ea[k >> 1]);
    }
    const h2 s2h = u2h(s2), s1h = u2h(s1), s0h = u2h(s0);
    h2 w[4];
#pragma unroll
    for (int k = 0; k < 4; ++k) {
        const h2 ve = u2h(v[2 * k]), vo = u2h(v[2 * k + 1]);
        w[k] = s2h * (vo - ve) + ve;
    }
    const h2 u0 = s1h * (w[1] - w[0]) + w[0];
    const h2 u1 = s1h * (w[3] - w[2]) + w[2];
    return h2u(s0h * (u1 - u0) + u0);
}

// decode pair index -> image, q, row pointer
static __device__ __forceinline__ const float* pair_ptr(const float* x, int pi, int& b, int& q) {
    const int p = 2 * pi;
    b = p / PPI;
    q = p - b * PPI;                 // even
    const int i = q / WPOUT;
    const int j = q - i * WPOUT;     // even -> 8B aligned; j<=26 so pair in-row
    return x + b * 1024 + i * 32 + j;
}

__global__ __launch_bounds__(THREADS, 4)
void dwn_conv_lut_kernel(const float* __restrict__ x,     // [32,1,32,32]
                         const float* __restrict__ lut0,  // [64,16,16]
                         const float* __restrict__ lut1,  // [64,4,16]
                         const float* __restrict__ lut2,  // [64,1,16]
                         const int*   __restrict__ idx0,  // [64,16,4]
                         const int*   __restrict__ idx1,  // [64,4,4]
                         const int*   __restrict__ idx2,  // [64,1,4]
                         float*       __restrict__ out)   // [32,64,28,28]
{
    __shared__ __align__(16) _Float16 lut[NNODE][16];     // [0..7]=e, [8..15]=d (f16)
    __shared__ float scratch[THREADS * SLICE];            // pair-B pipeline state

    const int tid = threadIdx.x;
    const int c   = blockIdx.y;

    // ---- stage sigmoided LUTs as f16 (e,d): 168 pairs over 128 threads ----
    for (int t = tid; t < NNODE * 8; t += THREADS) {
        const int k = t & 7, node = t >> 3;
        const float* src;
        if (node < 16)      src = lut0 + (c * 16 + node) * 16;
        else if (node < 20) src = lut1 + (c * 4 + (node - 16)) * 16;
        else                src = lut2 + c * 16;
        const float a = src[2 * k], b = src[2 * k + 1];
        const float ea = 1.0f / (1.0f + __expf(-a));
        const float eb = 1.0f / (1.0f + __expf(-b));
        lut[node][k]     = (_Float16)ea;
        lut[node][k + 8] = (_Float16)(eb - ea);
    }

    // ---- two pairs per thread: A in registers (movrel), B in the LDS slice ----
    const int piA = blockIdx.x * THREADS + tid;   // 49*128 == 6272, no tail
    const int piB = piA + HPAIR;

    int bA, qA, bB, qB;
    const float* rpA = pair_ptr(x, piA, bA, qA);
    const float* rpB = pair_ptr(x, piB, bB, qB);

    f32x32 pv;                                    // pair-A window (proven r12 shape)
    float* myB = &scratch[tid * SLICE];           // pair-B window + h0B
#pragma unroll
    for (int di = 0; di < KK; ++di) {
        const float2* a2 = (const float2*)(rpA + di * 32);
        const float2 a01 = a2[0], a23 = a2[1], a45 = a2[2];
        const float wa[6] = { a01.x, a01.y, a23.x, a23.y, a45.x, a45.y };
        const float2* b2 = (const float2*)(rpB + di * 32);
        const float2 b01 = b2[0], b23 = b2[1], b45 = b2[2];
        const float wb[6] = { b01.x, b01.y, b23.x, b23.y, b45.x, b45.y };
#pragma unroll
        for (int dj = 0; dj < KK; ++dj) {
            pv[di * 5 + dj]  = u2f(packpair(wa[dj], wa[dj + 1]));
            myB[di * 5 + dj] = u2f(packpair(wb[dj], wb[dj + 1]));
        }
    }

    __syncthreads();   // LUTs (and B slices) ready

    // ---- layer 0: 16 nodes; two INDEPENDENT chains per thread ----
    const int* id0 = idx0 + c * 64;   // block-uniform -> scalar loads
    f32x16 h0A;
#pragma unroll
    for (int m = 0; m < 16; ++m) {
        const uint4* row = (const uint4*)&lut[m][0];
        const uint4 E = row[0], D = row[1];
        const int i0 = __builtin_amdgcn_readfirstlane(id0[m * 4 + 0]);
        const int i1 = __builtin_amdgcn_readfirstlane(id0[m * 4 + 1]);
        const int i2 = __builtin_amdgcn_readfirstlane(id0[m * 4 + 2]);
        const int i3 = __builtin_amdgcn_readfirstlane(id0[m * 4 + 3]);
        // B gathers issue first (ds_read latency hides under A math)
        const unsigned b0 = f2u(myB[i0]);
        const unsigned b1 = f2u(myB[i1]);
        const unsigned b2 = f2u(myB[i2]);
        const unsigned b3 = f2u(myB[i3]);
        h0A[m] = u2f(node_pair(E, D, f2u(pv[i0]), f2u(pv[i1]), f2u(pv[i2]), f2u(pv[i3])));
        const unsigned rB = node_pair(E, D, b0, b1, b2, b3);
        myB[26 + m] = u2f(rB);        // h0B -> slice (imm-offset ds_write)
    }

    // ---- layer 1: 4 nodes; A from movrel h0A, B from slice ----
    const int* id1 = idx1 + c * 16;
    unsigned h1A[4], h1B[4];          // static-indexed only
#pragma unroll
    for (int m = 0; m < 4; ++m) {
        const uint4* row = (const uint4*)&lut[16 + m][0];
        const uint4 E = row[0], D = row[1];
        const int i0 = __builtin_amdgcn_readfirstlane(id1[m * 4 + 0]);
        const int i1 = __builtin_amdgcn_readfirstlane(id1[m * 4 + 1]);
        const int i2 = __builtin_amdgcn_readfirstlane(id1[m * 4 + 2]);
        const int i3 = __builtin_amdgcn_readfirstlane(id1[m * 4 + 3]);
        const unsigned b0 = f2u(myB[26 + i0]);
        const unsigned b1 = f2u(myB[26 + i1]);
        const unsigned b2 = f2u(myB[26 + i2]);
        const unsigned b3 = f2u(myB[26 + i3]);
        h1A[m] = node_pair(E, D, f2u(h0A[i0]), f2u(h0A[i1]), f2u(h0A[i2]), f2u(h0A[i3]));
        h1B[m] = node_pair(E, D, b0, b1, b2, b3);
    }

    // ---- layer 2: 1 node; 4-way uniform select (constant after unroll) ----
    const int* id2 = idx2 + c * 4;
    unsigned sA[4], sB[4];
#pragma unroll
    for (int jj = 0; jj < 4; ++jj) {
        const int ii = __builtin_amdgcn_readfirstlane(id2[jj]);
        sA[jj] = (ii == 0) ? h1A[0] : (ii == 1) ? h1A[1] : (ii == 2) ? h1A[2] : h1A[3];
        sB[jj] = (ii == 0) ? h1B[0] : (ii == 1) ? h1B[1] : (ii == 2) ? h1B[2] : h1B[3];
    }
    const uint4* row2 = (const uint4*)&lut[20][0];
    const uint4 E2 = row2[0], D2 = row2[1];
    const h2 rA = u2h(node_pair(E2, D2, sA[0], sA[1], sA[2], sA[3]));
    const h2 rB = u2h(node_pair(E2, D2, sB[0], sB[1], sB[2], sB[3]));

    // ---- stores: two consecutive q (q even) -> aligned float2, both pairs ----
    float2* oA = (float2*)(out + (bA * NCH + c) * PPI + qA);
    *oA = make_float2((float)rA[0], (float)rA[1]);
    float2* oB = (float2*)(out + (bB * NCH + c) * PPI + qB);
    *oB = make_float2((float)rB[0], (float)rB[1]);
}

extern "C" void kernel_launch(void* const* d_in, const int* in_sizes, int n_in,
                              void* d_out, int out_size, void* d_ws, size_t ws_size,
                              hipStream_t stream) {
    const float* x    = (const float*)d_in[0];
    const float* lut0 = (const float*)d_in[1];
    const float* lut1 = (const float*)d_in[2];
    const float* lut2 = (const float*)d_in[3];
    const int*   idx0 = (const int*)d_in[4];
    const int*   idx1 = (const int*)d_in[5];
    const int*   idx2 = (const int*)d_in[6];
    float* out = (float*)d_out;

    dim3 grid(HPAIR / THREADS, NCH);   // 49 x 64
    dim3 block(THREADS);
    dwn_conv_lut_kernel<<<grid, block, 0, stream>>>(x, lut0, lut1, lut2,
                                                    idx0, idx1, idx2, out);
}